// Round 1
// baseline (111.641 us; speedup 1.0000x reference)
//
#include <hip/hip_runtime.h>
#include <hip/hip_bf16.h>
#include <cstdint>

// LSTM cell, B=16384, IN=512, H=512.
// Plan: prepass casts x|h -> bf16 A[16384][1024] (chunk-swizzled) and
// W_g -> bf16 W^T[4][512][1024] (chunk-swizzled); one fused MFMA GEMM kernel
// computes all 4 gates per wave and applies the LSTM epilogue in-register.

typedef __attribute__((ext_vector_type(8))) __bf16 bf16x8;
typedef __attribute__((ext_vector_type(4))) float f32x4;

#define GLOAD_LDS16(gp, lp)                                                        \
    __builtin_amdgcn_global_load_lds(                                              \
        (const __attribute__((address_space(1))) void*)(gp),                       \
        (__attribute__((address_space(3))) void*)(lp), 16, 0, 0)

__device__ __forceinline__ unsigned short f2bf(float f) {
    unsigned int u = __float_as_uint(f);
    u = (u + 0x7FFFu + ((u >> 16) & 1u)) >> 16;   // RNE
    return (unsigned short)u;
}
__device__ __forceinline__ unsigned int pk2(float a, float b) {
    return (unsigned int)f2bf(a) | ((unsigned int)f2bf(b) << 16);
}
__device__ __forceinline__ float tanh_fast(float x) {
    float ax = fabsf(x);
    float e  = __expf(2.f * ax);
    float t  = 1.f - 2.f / (e + 1.f);   // e=inf -> t=1, no NaN
    return copysignf(t, x);
}

// ---------- prepass: A = bf16([x | h]), swizzled 16B chunks ----------
// Layout: A[r][1024]; within each 64-col group, 16B chunk j holds source
// chunk j ^ (r&7). Then global_load_lds (linear) + ds_read with XOR is
// bank-conflict-free (T2 / rule #21).
__global__ __launch_bounds__(256) void conv_a_kernel(const float* __restrict__ x,
                                                     const float* __restrict__ h,
                                                     unsigned short* __restrict__ A) {
    int tc = blockIdx.x * 256 + threadIdx.x;   // 16384*128 = 2,097,152 chunks
    int r  = tc >> 7;
    int c  = tc & 127;                          // 16B chunk index within row
    int j  = c & 7;
    int jj = j ^ (r & 7);
    int col = (c >> 3) * 64 + jj * 8;           // source column (0..1023)
    const float* src = (col < 512) ? (x + (size_t)r * 512 + col)
                                   : (h + (size_t)r * 512 + (col - 512));
    const float4* s4 = reinterpret_cast<const float4*>(src);
    float4 v0 = s4[0];
    float4 v1 = s4[1];
    uint4 o;
    o.x = pk2(v0.x, v0.y); o.y = pk2(v0.z, v0.w);
    o.z = pk2(v1.x, v1.y); o.w = pk2(v1.z, v1.w);
    *reinterpret_cast<uint4*>(A + (size_t)r * 1024 + (size_t)c * 8) = o;
}

// ---------- prepass: Wt[g][n][k] = bf16(W_g[k][n]), swizzled by n&7 ----------
__global__ __launch_bounds__(256) void conv_w_kernel(const float* __restrict__ w0,
                                                     const float* __restrict__ w1,
                                                     const float* __restrict__ w2,
                                                     const float* __restrict__ w3,
                                                     unsigned short* __restrict__ Wt) {
    int tc = blockIdx.x * 256 + threadIdx.x;   // 4*512*128 = 262,144 chunks
    int g  = tc >> 16;
    int n  = (tc >> 7) & 511;
    int c  = tc & 127;
    int j  = c & 7;
    int jj = j ^ (n & 7);
    int k0 = (c >> 3) * 64 + jj * 8;
    const float* Wg = (g == 0) ? w0 : (g == 1) ? w1 : (g == 2) ? w2 : w3;
    unsigned short us[8];
    #pragma unroll
    for (int u = 0; u < 8; ++u) us[u] = f2bf(Wg[(k0 + u) * 512 + n]);
    uint4 o;
    o.x = (unsigned)us[0] | ((unsigned)us[1] << 16);
    o.y = (unsigned)us[2] | ((unsigned)us[3] << 16);
    o.z = (unsigned)us[4] | ((unsigned)us[5] << 16);
    o.w = (unsigned)us[6] | ((unsigned)us[7] << 16);
    *reinterpret_cast<uint4*>(Wt + (size_t)g * 524288 + (size_t)n * 1024 + (size_t)c * 8) = o;
}

// ---------- fused LSTM GEMM ----------
// Block tile: 128 rows x 64 h-cols x 4 gates. 4 waves (2M x 2N); each wave:
// 64 rows x 32 cols x 4 gates -> acc[4][4][2] f32x4 (128 VGPR).
// LDS: As[128][64] bf16 (16KB) + Bs[4][64 n][64 k] bf16 (32KB), swizzled.
__global__ __launch_bounds__(256, 2) void lstm_gemm_kernel(
    const unsigned short* __restrict__ A,    // [16384][1024] bf16, swizzled
    const unsigned short* __restrict__ Wt,   // [4][512][1024]  bf16, swizzled
    const float* __restrict__ c_cur,
    const float* __restrict__ bi_p, const float* __restrict__ bf_p,
    const float* __restrict__ bo_p, const float* __restrict__ bc_p,
    float* __restrict__ h_out, float* __restrict__ c_out)
{
    __shared__ char smem[49152];
    const int tid  = threadIdx.x;
    const int lane = tid & 63;
    const int wid  = tid >> 6;
    const int wm   = wid >> 1;   // 0..1 (M)
    const int wn   = wid & 1;    // 0..1 (N)

    // XCD-aware bijective swizzle: 1024 blocks, 8 XCDs, 128 per XCD
    const int bid  = blockIdx.x;
    const int orig = (bid & 7) * 128 + (bid >> 3);
    const int rb   = orig >> 3;   // 0..127
    const int cb   = orig & 7;    // 0..7
    const int row0 = rb * 128;
    const int n0   = cb * 64;

    const int q = tid >> 3;                         // 0..31
    const char* Abase = (const char*)A + ((size_t)(row0 + q) << 11) + (size_t)(tid & 7) * 16;
    const char* Wbase = (const char*)Wt + (size_t)(tid & 7) * 16;

    f32x4 acc[4][4][2];
    #pragma unroll
    for (int g = 0; g < 4; ++g)
        #pragma unroll
        for (int m = 0; m < 4; ++m)
            #pragma unroll
            for (int n = 0; n < 2; ++n)
                acc[g][m][n] = (f32x4){0.f, 0.f, 0.f, 0.f};

    #pragma unroll 1
    for (int kt = 0; kt < 16; ++kt) {
        __syncthreads();
        // stage A tile: 16KB, 4 x (wave64 x 16B)
        #pragma unroll
        for (int it = 0; it < 4; ++it) {
            const char* gp = Abase + (size_t)it * (32 * 2048) + (size_t)kt * 128;
            char* lp = smem + it * 4096 + wid * 1024;
            GLOAD_LDS16(gp, lp);
        }
        // stage B tiles (4 gates): 32KB, 8 x (wave64 x 16B)
        #pragma unroll
        for (int it = 0; it < 8; ++it) {
            int idx = it * 32 + q;  // 0..255 : g = idx>>6, n = idx&63
            const char* gp = Wbase + (size_t)(idx >> 6) * 1048576
                           + (size_t)(n0 + (idx & 63)) * 2048 + (size_t)kt * 128;
            char* lp = smem + 16384 + it * 4096 + wid * 1024;
            GLOAD_LDS16(gp, lp);
        }
        __syncthreads();  // compiler drains vmcnt before barrier

        #pragma unroll
        for (int ks = 0; ks < 2; ++ks) {
            const int kb = ks * 64 + ((lane >> 4) << 4);
            bf16x8 aF[4];
            #pragma unroll
            for (int m = 0; m < 4; ++m) {
                int row = wm * 64 + m * 16 + (lane & 15);
                int off = row * 128 + (kb ^ ((row & 7) << 4));
                aF[m] = *reinterpret_cast<const bf16x8*>(smem + off);
            }
            #pragma unroll
            for (int g = 0; g < 4; ++g) {
                #pragma unroll
                for (int n = 0; n < 2; ++n) {
                    int colr = wn * 32 + n * 16 + (lane & 15);
                    int off  = 16384 + g * 8192 + colr * 128 + (kb ^ ((colr & 7) << 4));
                    bf16x8 bF = *reinterpret_cast<const bf16x8*>(smem + off);
                    #pragma unroll
                    for (int m = 0; m < 4; ++m)
                        acc[g][m][n] = __builtin_amdgcn_mfma_f32_16x16x32_bf16(
                            aF[m], bF, acc[g][m][n], 0, 0, 0);
                }
            }
        }
    }

    // fused LSTM epilogue: all 4 gates are in-lane
    const int cl = lane & 15;
    const int r4 = (lane >> 4) * 4;
    #pragma unroll
    for (int n = 0; n < 2; ++n) {
        const int col = n0 + wn * 32 + n * 16 + cl;
        const float bi = bi_p[col], bfv = bf_p[col], bo = bo_p[col], bc = bc_p[col];
        #pragma unroll
        for (int m = 0; m < 4; ++m) {
            const int rowb = row0 + wm * 64 + m * 16 + r4;
            #pragma unroll
            for (int rr = 0; rr < 4; ++rr) {
                const size_t o = (size_t)(rowb + rr) * 512 + col;
                float gi = acc[0][m][n][rr] + bi;
                float gf = acc[1][m][n][rr] + bfv;
                float go = acc[2][m][n][rr] + bo;
                float gc = acc[3][m][n][rr] + bc;
                float is = 1.f / (1.f + __expf(-gi));
                float fs = 1.f / (1.f + __expf(-gf));
                float os = 1.f / (1.f + __expf(-go));
                float ct = tanh_fast(gc);
                float cn = fs * c_cur[o] + is * ct;
                h_out[o] = os * tanh_fast(cn);
                c_out[o] = cn;
            }
        }
    }
}

extern "C" void kernel_launch(void* const* d_in, const int* in_sizes, int n_in,
                              void* d_out, int out_size, void* d_ws, size_t ws_size,
                              hipStream_t stream) {
    const float* x   = (const float*)d_in[0];
    const float* h   = (const float*)d_in[1];
    const float* c   = (const float*)d_in[2];
    const float* W_i = (const float*)d_in[3];
    const float* b_i = (const float*)d_in[4];
    const float* W_f = (const float*)d_in[5];
    const float* b_f = (const float*)d_in[6];
    const float* W_o = (const float*)d_in[7];
    const float* b_o = (const float*)d_in[8];
    const float* W_c = (const float*)d_in[9];
    const float* b_c = (const float*)d_in[10];

    unsigned short* Aswz = (unsigned short*)d_ws;                      // 33,554,432 B
    unsigned short* Wt   = (unsigned short*)((char*)d_ws + 33554432);  //  4,194,304 B

    float* h_out = (float*)d_out;                    // [16384][512]
    float* c_out = h_out + (size_t)16384 * 512;      // [16384][512]

    conv_a_kernel<<<8192, 256, 0, stream>>>(x, h, Aswz);
    conv_w_kernel<<<1024, 256, 0, stream>>>(W_i, W_f, W_o, W_c, Wt);
    lstm_gemm_kernel<<<1024, 256, 0, stream>>>(Aswz, Wt, c, b_i, b_f, b_o, b_c,
                                               h_out, c_out);
}

// Round 2
// 109.191 us; speedup vs baseline: 1.0224x; 1.0224x over previous
//
#include <hip/hip_runtime.h>
#include <hip/hip_bf16.h>
#include <cstdint>

// LSTM cell, B=16384, IN=512, H=512, fused 4-gate bf16 MFMA GEMM.
// 8-phase 256^2 template (T2+T3+T4+T5): BM=256 rows, BN=64 h * 4 gates,
// BK=64 (2 k-slices of 32), 8 waves, 128KB double-buffered LDS, counted vmcnt.

typedef __attribute__((ext_vector_type(8))) __bf16 bf16x8;
typedef __attribute__((ext_vector_type(4))) float f32x4;

#define GLOAD_LDS16(gp, lp)                                                        \
    __builtin_amdgcn_global_load_lds(                                              \
        (const __attribute__((address_space(1))) void*)(gp),                       \
        (__attribute__((address_space(3))) void*)(lp), 16, 0, 0)

#define BAR()  asm volatile("s_barrier" ::: "memory")
#define VMW4() asm volatile("s_waitcnt vmcnt(4)" ::: "memory")
#define VMW0() asm volatile("s_waitcnt vmcnt(0)" ::: "memory")

__device__ __forceinline__ unsigned short f2bf(float f) {
    unsigned int u = __float_as_uint(f);
    u = (u + 0x7FFFu + ((u >> 16) & 1u)) >> 16;   // RNE
    return (unsigned short)u;
}
__device__ __forceinline__ float tanh_fast(float x) {
    float ax = fabsf(x);
    float e  = __expf(2.f * ax);
    float t  = 1.f - 2.f / (e + 1.f);   // e=inf -> t=1, no NaN
    return copysignf(t, x);
}

// ---------------- prepass A ----------------
// A_pre: [mt=64][kt=16][ks=2] 16KB slices. Slice position p (0..1023, 16B):
//   row = p>>2 (0..255), kchunk c = (p&3) ^ ((row>>1)&3)
//   holds bf16[8] = combined[mt*256+row][kt*64 + ks*32 + c*8 .. +8]
// combined[:,k] = x[:,k] (k<512) else h[:,k-512].
__global__ __launch_bounds__(256) void conv_a_kernel(const float* __restrict__ x,
                                                     const float* __restrict__ h,
                                                     unsigned short* __restrict__ A) {
    int G  = blockIdx.x * 256 + threadIdx.x;   // 2,097,152 chunks
    int b  = G >> 10;                           // slice id (0..2047)
    int p  = G & 1023;
    int mt = b >> 5;
    int kt = (b >> 1) & 15;
    int ks = b & 1;
    int row = p >> 2;
    int c   = (p & 3) ^ ((row >> 1) & 3);
    int r   = mt * 256 + row;
    int k0  = kt * 64 + ks * 32 + c * 8;
    const float* src = (k0 < 512) ? (x + (size_t)r * 512 + k0)
                                  : (h + (size_t)r * 512 + (k0 - 512));
    const float4* s4 = reinterpret_cast<const float4*>(src);
    float4 v0 = s4[0];
    float4 v1 = s4[1];
    uint4 o;
    o.x = (unsigned)f2bf(v0.x) | ((unsigned)f2bf(v0.y) << 16);
    o.y = (unsigned)f2bf(v0.z) | ((unsigned)f2bf(v0.w) << 16);
    o.z = (unsigned)f2bf(v1.x) | ((unsigned)f2bf(v1.y) << 16);
    o.w = (unsigned)f2bf(v1.z) | ((unsigned)f2bf(v1.w) << 16);
    *reinterpret_cast<uint4*>(A + ((size_t)b * 1024 + p) * 8) = o;
}

// ---------------- prepass B ----------------
// B_pre: [nb=8][kt=16][ks=2] 16KB slices. position p:
//   col = p>>2 (0..255) = g*64 + hh,  c = (p&3) ^ ((col>>1)&3)
//   holds bf16[8] = W_g[kt*64+ks*32+c*8 + u][nb*64+hh], u=0..7
__global__ __launch_bounds__(256) void conv_w_kernel(const float* __restrict__ w0,
                                                     const float* __restrict__ w1,
                                                     const float* __restrict__ w2,
                                                     const float* __restrict__ w3,
                                                     unsigned short* __restrict__ Wt) {
    int G  = blockIdx.x * 256 + threadIdx.x;   // 262,144 chunks
    int b  = G >> 10;                           // 0..255
    int p  = G & 1023;
    int nb = b >> 5;
    int kt = (b >> 1) & 15;
    int ks = b & 1;
    int col = p >> 2;
    int c   = (p & 3) ^ ((col >> 1) & 3);
    int g   = col >> 6;
    int hh  = col & 63;
    int n   = nb * 64 + hh;
    int k0  = kt * 64 + ks * 32 + c * 8;
    const float* Wg = (g == 0) ? w0 : (g == 1) ? w1 : (g == 2) ? w2 : w3;
    unsigned short us[8];
    #pragma unroll
    for (int u = 0; u < 8; ++u) us[u] = f2bf(Wg[(size_t)(k0 + u) * 512 + n]);
    uint4 o;
    o.x = (unsigned)us[0] | ((unsigned)us[1] << 16);
    o.y = (unsigned)us[2] | ((unsigned)us[3] << 16);
    o.z = (unsigned)us[4] | ((unsigned)us[5] << 16);
    o.w = (unsigned)us[6] | ((unsigned)us[7] << 16);
    *reinterpret_cast<uint4*>(Wt + ((size_t)b * 1024 + p) * 8) = o;
}

// ---------------- fused 8-phase GEMM ----------------
// LDS map (128KB): A: dbuf*32768 + ks*16384 + p*16   (dbuf in {0,1})
//                  B: 65536 + dbuf*32768 + ks*16384 + p*16
__global__ __launch_bounds__(512, 2) void lstm_gemm8(
    const char* __restrict__ Apre, const char* __restrict__ Bpre,
    const float* __restrict__ c_cur,
    const float* __restrict__ bi_p, const float* __restrict__ bf_p,
    const float* __restrict__ bo_p, const float* __restrict__ bc_p,
    float* __restrict__ h_out, float* __restrict__ c_out)
{
    extern __shared__ char smem[];
    const int tid  = threadIdx.x;
    const int lane = tid & 63;
    const int wid  = tid >> 6;    // 0..7
    const int wm   = wid >> 2;    // 0..1  (row half)
    const int wn   = wid & 3;     // 0..3  (16-h slot)

    // XCD swizzle: 512 blocks, blocks on one XCD share nb (B panel L2-resident)
    const int orig = (blockIdx.x & 7) * 64 + (blockIdx.x >> 3);
    const int nb   = orig >> 6;   // 0..7
    const int mt   = orig & 63;   // 0..63

    const int ar   = lane & 15;
    const int swz  = ((lane >> 4) ^ ((ar >> 1) & 3)) << 4;
    const int aoffb = ar * 64 + swz;
    const int boffb = (wn * 16 + ar) * 64 + swz;
    const int swl   = wid * 1024;

    const char* ApreB = Apre + (((size_t)mt * 32) << 14) + (size_t)tid * 16;
    const char* BpreB = Bpre + (((size_t)nb * 32) << 14) + (size_t)tid * 16;

#define STAGE_A(ktks, dstb) {                                           \
        const char* gp_ = ApreB + (((size_t)(ktks)) << 14);             \
        GLOAD_LDS16(gp_,        smem + (dstb) + swl);                   \
        GLOAD_LDS16(gp_ + 8192, smem + (dstb) + 8192 + swl); }
#define STAGE_B(ktks, dstb) {                                           \
        const char* gp_ = BpreB + (((size_t)(ktks)) << 14);             \
        GLOAD_LDS16(gp_,        smem + (dstb) + swl);                   \
        GLOAD_LDS16(gp_ + 8192, smem + (dstb) + 8192 + swl); }

    f32x4 acc[4][8];   // [gate][m-frag]
    #pragma unroll
    for (int g = 0; g < 4; ++g)
        #pragma unroll
        for (int m = 0; m < 8; ++m)
            acc[g][m] = (f32x4){0.f, 0.f, 0.f, 0.f};

    bf16x8 aFr[4], bFr[4];

#define LDA(mh, ksb, curb)                                              \
    _Pragma("unroll")                                                   \
    for (int mi = 0; mi < 4; ++mi)                                      \
        aFr[mi] = *reinterpret_cast<const bf16x8*>(                     \
            smem + (curb) + (ksb) +                                     \
            (wm * 8192 + (mh) * 4096 + mi * 1024) + aoffb);
#define LDB(ksb, curb)                                                  \
    _Pragma("unroll")                                                   \
    for (int g = 0; g < 4; ++g)                                         \
        bFr[g] = *reinterpret_cast<const bf16x8*>(                      \
            smem + 65536 + (curb) + (ksb) + g * 4096 + boffb);
#define MM(mh)                                                          \
    _Pragma("unroll")                                                   \
    for (int g = 0; g < 4; ++g)                                         \
        _Pragma("unroll")                                               \
        for (int mi = 0; mi < 4; ++mi)                                  \
            acc[g][(mh) * 4 + mi] = __builtin_amdgcn_mfma_f32_16x16x32_bf16( \
                aFr[mi], bFr[g], acc[g][(mh) * 4 + mi], 0, 0, 0);

    // prologue: stage K-tile 0 (both k-slices) into buf0
    STAGE_A(0, 0);
    STAGE_B(0, 65536);
    STAGE_A(1, 16384);
    STAGE_B(1, 65536 + 16384);
    VMW4();        // drain slice-pair (0, ks0); pair (0, ks1) stays in flight
    BAR();

    #pragma unroll 1
    for (int t = 0; t < 16; ++t) {
        const int cur  = (t & 1) << 15;
        const int nxt  = cur ^ 32768;
        const int k2   = (t + 1) * 2;
        const bool more = (t < 15);

        // phase 0: ks=0, m 0..3  | prefetch A(t+1, ks0)
        LDA(0, 0, cur); LDB(0, cur);
        if (more) STAGE_A(k2, nxt);
        BAR();
        __builtin_amdgcn_s_setprio(1);
        MM(0);
        __builtin_amdgcn_s_setprio(0);
        BAR();

        // phase 1: ks=0, m 4..7  | prefetch B(t+1, ks0); drain pair(t, ks1)
        LDA(1, 0, cur);
        if (more) STAGE_B(k2, 65536 + nxt);
        BAR();
        __builtin_amdgcn_s_setprio(1);
        MM(1);
        __builtin_amdgcn_s_setprio(0);
        if (more) { VMW4(); } else { VMW0(); }
        BAR();

        // phase 2: ks=1, m 0..3  | prefetch A(t+1, ks1)
        LDA(0, 16384, cur); LDB(16384, cur);
        if (more) STAGE_A(k2 + 1, 16384 + nxt);
        BAR();
        __builtin_amdgcn_s_setprio(1);
        MM(0);
        __builtin_amdgcn_s_setprio(0);
        BAR();

        // phase 3: ks=1, m 4..7  | prefetch B(t+1, ks1); drain pair(t+1, ks0)
        LDA(1, 16384, cur);
        if (more) STAGE_B(k2 + 1, 65536 + 16384 + nxt);
        BAR();
        __builtin_amdgcn_s_setprio(1);
        MM(1);
        __builtin_amdgcn_s_setprio(0);
        if (more) VMW4();
        BAR();
    }

    // fused LSTM epilogue: all 4 gates in-lane
    const int r4   = (lane >> 4) * 4;
    const int hcol = nb * 64 + wn * 16 + ar;
    const float bii = bi_p[hcol], bff = bf_p[hcol];
    const float boo = bo_p[hcol], bcc = bc_p[hcol];
    #pragma unroll
    for (int m = 0; m < 8; ++m) {
        const int rowb = mt * 256 + wm * 128 + m * 16 + r4;
        #pragma unroll
        for (int rr = 0; rr < 4; ++rr) {
            const size_t o = (size_t)(rowb + rr) * 512 + hcol;
            float gi = acc[0][m][rr] + bii;
            float gf = acc[1][m][rr] + bff;
            float go = acc[2][m][rr] + boo;
            float gc = acc[3][m][rr] + bcc;
            float is = 1.f / (1.f + __expf(-gi));
            float fs = 1.f / (1.f + __expf(-gf));
            float os = 1.f / (1.f + __expf(-go));
            float ct = tanh_fast(gc);
            float cn = fs * c_cur[o] + is * ct;
            h_out[o] = os * tanh_fast(cn);
            c_out[o] = cn;
        }
    }
#undef STAGE_A
#undef STAGE_B
#undef LDA
#undef LDB
#undef MM
}

extern "C" void kernel_launch(void* const* d_in, const int* in_sizes, int n_in,
                              void* d_out, int out_size, void* d_ws, size_t ws_size,
                              hipStream_t stream) {
    const float* x   = (const float*)d_in[0];
    const float* h   = (const float*)d_in[1];
    const float* c   = (const float*)d_in[2];
    const float* W_i = (const float*)d_in[3];
    const float* b_i = (const float*)d_in[4];
    const float* W_f = (const float*)d_in[5];
    const float* b_f = (const float*)d_in[6];
    const float* W_o = (const float*)d_in[7];
    const float* b_o = (const float*)d_in[8];
    const float* W_c = (const float*)d_in[9];
    const float* b_c = (const float*)d_in[10];

    unsigned short* Apre = (unsigned short*)d_ws;                      // 33,554,432 B
    unsigned short* Bpre = (unsigned short*)((char*)d_ws + 33554432);  //  4,194,304 B

    float* h_out = (float*)d_out;
    float* c_out = h_out + (size_t)16384 * 512;

    // allow 128KB dynamic LDS (deterministic, capture-safe host call)
    (void)hipFuncSetAttribute(reinterpret_cast<const void*>(lstm_gemm8),
                              hipFuncAttributeMaxDynamicSharedMemorySize, 131072);

    conv_a_kernel<<<8192, 256, 0, stream>>>(x, h, Apre);
    conv_w_kernel<<<1024, 256, 0, stream>>>(W_i, W_f, W_o, W_c, Bpre);
    lstm_gemm8<<<512, 512, 131072, stream>>>((const char*)Apre, (const char*)Bpre,
                                             c, b_i, b_f, b_o, b_c, h_out, c_out);
}